// Round 1
// baseline (375.565 us; speedup 1.0000x reference)
//
#include <hip/hip_runtime.h>

// MoE FFN: B=2,T=1024,D=1024, E=32,H=256,TOPK=4, S=2,HS=1024. N=2048 tokens.
// Strategy: bf16 MFMA everywhere. Pre-convert weights+x to bf16 in ws.
// Router -> per-expert gather lists -> grouped GEMM swiglu -> down-proj (atomic add)
// Shared experts: dense GEMM swiglu -> down-proj (read-modify-write after routed).

#define N_TOK 2048
#define DDIM 1024
#define NEXP 32
#define HDIM 256
#define TOPK 4
#define NSH 2
#define HSH 1024

typedef unsigned short us4 __attribute__((ext_vector_type(4)));
typedef unsigned short us8 __attribute__((ext_vector_type(8)));
typedef short bf16x8 __attribute__((ext_vector_type(8)));
typedef float f32x4 __attribute__((ext_vector_type(4)));

__device__ __forceinline__ unsigned short f2bf(float f) {
  union { float f; unsigned u; } v; v.f = f;
  unsigned r = v.u + 0x7fffu + ((v.u >> 16) & 1u);   // RNE
  return (unsigned short)(r >> 16);
}

// ---------------- fp32 -> bf16 conversion ----------------
__global__ void k_cvt(const float* __restrict__ src, unsigned short* __restrict__ dst, int n4) {
  int i = blockIdx.x * 256 + threadIdx.x;
  if (i >= n4) return;
  float4 v = reinterpret_cast<const float4*>(src)[i];
  us4 o;
  o[0] = f2bf(v.x); o[1] = f2bf(v.y); o[2] = f2bf(v.z); o[3] = f2bf(v.w);
  reinterpret_cast<us4*>(dst)[i] = o;
}

// ---------------- router ----------------
// one block per token: logits = x . Wr^T, top4 on (logits+bias), weights = softmax
// over the selected raw logits (full-softmax renormalization cancels).
__global__ __launch_bounds__(256) void k_router(const float* __restrict__ x,
                                                const float* __restrict__ Wr,
                                                const float* __restrict__ rb,
                                                int* __restrict__ cnt,
                                                int* __restrict__ ent,
                                                float* __restrict__ wgt) {
  int tok = blockIdx.x;
  __shared__ float sX[DDIM];
  __shared__ float sLog[NEXP];
  int tid = threadIdx.x;
  {
    float4 v = *reinterpret_cast<const float4*>(x + tok * DDIM + tid * 4);
    *reinterpret_cast<float4*>(sX + tid * 4) = v;
  }
  __syncthreads();
  int wid = tid >> 6, lane = tid & 63;
  for (int ee = 0; ee < 8; ee++) {
    int e = wid * 8 + ee;
    float p = 0.f;
    for (int d = lane; d < DDIM; d += 64) p += sX[d] * Wr[e * DDIM + d];
#pragma unroll
    for (int off = 32; off; off >>= 1) p += __shfl_xor(p, off);
    if (lane == 0) sLog[e] = p;
  }
  __syncthreads();
  if (tid == 0) {
    int usedmask = 0;
    int idx[TOPK]; float lv[TOPK];
#pragma unroll
    for (int k = 0; k < TOPK; k++) {
      float best = -3.4e38f; int bi = 0;
      for (int e = 0; e < NEXP; e++) {
        if ((usedmask >> e) & 1) continue;
        float v = sLog[e] + rb[e];
        if (v > best) { best = v; bi = e; }
      }
      usedmask |= 1 << bi; idx[k] = bi; lv[k] = sLog[bi];
    }
    float m = fmaxf(fmaxf(lv[0], lv[1]), fmaxf(lv[2], lv[3]));
    float w[TOPK]; float ssum = 0.f;
#pragma unroll
    for (int k = 0; k < TOPK; k++) { w[k] = __expf(lv[k] - m); ssum += w[k]; }
    float inv = 1.f / ssum;
#pragma unroll
    for (int k = 0; k < TOPK; k++) {
      int e = idx[k];
      int pos = atomicAdd(&cnt[e], 1);
      ent[e * N_TOK + pos] = tok * TOPK + k;
      wgt[e * N_TOK + pos] = w[k] * inv;
    }
  }
}

// ---------------- routed gate+up (+swiglu) ----------------
// grid (expert, tile). tile = 64 gathered rows. 512 cols = 256 g + 256 u interleaved
// so that wave-frag f holds g and frag f+8 holds u for the same h (in-register swiglu).
// LDS tiles padded to 40-ushort rows (80B) to break bank-conflict strides.
__global__ __launch_bounds__(512) void k_routed_gu(const unsigned short* __restrict__ xb,
                                                   const unsigned short* __restrict__ Wgb,
                                                   const unsigned short* __restrict__ Wub,
                                                   const int* __restrict__ cnt,
                                                   const int* __restrict__ ent,
                                                   const float* __restrict__ wgt,
                                                   unsigned short* __restrict__ hw) {
  int e = blockIdx.x, tile = blockIdx.y;
  int ne = cnt[e];
  if (tile * 64 >= ne) return;
  __shared__ unsigned short sA[64 * 40];
  __shared__ unsigned short sB[512 * 40];
  __shared__ int sTok[64];
  __shared__ float sW[64];
  int tid = threadIdx.x, lane = tid & 63, wid = tid >> 6;
  int wr = wid >> 1, wc = wid & 1;
  if (tid < 64) {
    int pos = tile * 64 + tid;
    int p2 = min(pos, ne - 1);
    sTok[tid] = ent[e * N_TOK + p2];
    sW[tid] = (pos < ne) ? wgt[e * N_TOK + p2] : 0.f;
  }
  __syncthreads();
  f32x4 zero = {0.f, 0.f, 0.f, 0.f};
  f32x4 acc[16];
#pragma unroll
  for (int f = 0; f < 16; f++) acc[f] = zero;

  for (int k0 = 0; k0 < DDIM; k0 += 32) {
    { // stage A (gathered x rows)
      int r = tid >> 3, l8 = tid & 7;
      int tok = sTok[r] >> 2;
      us4 v = *reinterpret_cast<const us4*>(xb + tok * DDIM + k0 + l8 * 4);
      *reinterpret_cast<us4*>(sA + r * 40 + l8 * 4) = v;
    }
    { // stage B: col c -> (sel g/u, h = (c/256)*128 + (c%128))
      int rr = tid >> 2, l4 = tid & 3;
#pragma unroll
      for (int p = 0; p < 4; p++) {
        int c = rr + p * 128;
        int sel = (c >> 7) & 1;
        int h = ((c >> 8) << 7) | (c & 127);
        const unsigned short* Wb = sel ? Wub : Wgb;
        us8 v = *reinterpret_cast<const us8*>(Wb + (e * HDIM + h) * DDIM + k0 + l4 * 8);
        *reinterpret_cast<us8*>(sB + c * 40 + l4 * 8) = v;
      }
    }
    __syncthreads();
    int ka = (lane >> 4) * 8;
    bf16x8 a = *reinterpret_cast<const bf16x8*>(sA + (wr * 16 + (lane & 15)) * 40 + ka);
#pragma unroll
    for (int f = 0; f < 16; f++) {
      bf16x8 b = *reinterpret_cast<const bf16x8*>(sB + (wc * 256 + f * 16 + (lane & 15)) * 40 + ka);
      acc[f] = __builtin_amdgcn_mfma_f32_16x16x32_bf16(a, b, acc[f], 0, 0, 0);
    }
    __syncthreads();
  }
  // epilogue: h = silu(g)*u*w, store bf16 at hw[token*4+slot][h]
#pragma unroll
  for (int f = 0; f < 8; f++) {
#pragma unroll
    for (int r = 0; r < 4; r++) {
      int tl = wr * 16 + (lane >> 4) * 4 + r;
      int pos = tile * 64 + tl;
      if (pos < ne) {
        float g = acc[f][r], u = acc[f + 8][r];
        float w = sW[tl];
        float hval = (g / (1.f + __expf(-g))) * u * w;
        int ts = sTok[tl];
        int hcol = wc * 128 + f * 16 + (lane & 15);
        hw[ts * HDIM + hcol] = f2bf(hval);
      }
    }
  }
}

// ---------------- routed down-proj (atomic scatter-add) ----------------
__global__ __launch_bounds__(512) void k_routed_down(const unsigned short* __restrict__ hw,
                                                     const unsigned short* __restrict__ Wdb,
                                                     const int* __restrict__ cnt,
                                                     const int* __restrict__ ent,
                                                     float* __restrict__ out) {
  int e = blockIdx.x, tile = blockIdx.y, dh = blockIdx.z;
  int ne = cnt[e];
  if (tile * 64 >= ne) return;
  __shared__ unsigned short sA[64 * 40];
  __shared__ unsigned short sB[512 * 40];
  __shared__ int sTok[64];
  int tid = threadIdx.x, lane = tid & 63, wid = tid >> 6;
  int wr = wid >> 1, wc = wid & 1;
  if (tid < 64) {
    int pos = tile * 64 + tid;
    int p2 = min(pos, ne - 1);
    sTok[tid] = ent[e * N_TOK + p2];
  }
  __syncthreads();
  f32x4 zero = {0.f, 0.f, 0.f, 0.f};
  f32x4 acc[16];
#pragma unroll
  for (int f = 0; f < 16; f++) acc[f] = zero;

  for (int k0 = 0; k0 < HDIM; k0 += 32) {
    {
      int r = tid >> 3, l8 = tid & 7;
      int row = sTok[r];
      us4 v = *reinterpret_cast<const us4*>(hw + row * HDIM + k0 + l8 * 4);
      *reinterpret_cast<us4*>(sA + r * 40 + l8 * 4) = v;
    }
    {
      int rr = tid >> 2, l4 = tid & 3;
#pragma unroll
      for (int p = 0; p < 4; p++) {
        int c = rr + p * 128;
        int d = dh * 512 + c;
        us8 v = *reinterpret_cast<const us8*>(Wdb + (e * DDIM + d) * HDIM + k0 + l4 * 8);
        *reinterpret_cast<us8*>(sB + c * 40 + l4 * 8) = v;
      }
    }
    __syncthreads();
    int ka = (lane >> 4) * 8;
    bf16x8 a = *reinterpret_cast<const bf16x8*>(sA + (wr * 16 + (lane & 15)) * 40 + ka);
#pragma unroll
    for (int f = 0; f < 16; f++) {
      bf16x8 b = *reinterpret_cast<const bf16x8*>(sB + (wc * 256 + f * 16 + (lane & 15)) * 40 + ka);
      acc[f] = __builtin_amdgcn_mfma_f32_16x16x32_bf16(a, b, acc[f], 0, 0, 0);
    }
    __syncthreads();
  }
#pragma unroll
  for (int f = 0; f < 16; f++) {
#pragma unroll
    for (int r = 0; r < 4; r++) {
      int tl = wr * 16 + (lane >> 4) * 4 + r;
      int pos = tile * 64 + tl;
      if (pos < ne) {
        int tok = sTok[tl] >> 2;
        int d = dh * 512 + wc * 256 + f * 16 + (lane & 15);
        atomicAdd(out + tok * DDIM + d, acc[f][r]);
      }
    }
  }
}

// ---------------- shared gate+up (+swiglu) ----------------
// grid (mtile 0..31, y = s*4 + htile). Block covers 64 tokens x 256 h (g+u).
__global__ __launch_bounds__(512) void k_shared_gu(const unsigned short* __restrict__ xb,
                                                   const unsigned short* __restrict__ Sgb,
                                                   const unsigned short* __restrict__ Sub,
                                                   unsigned short* __restrict__ hs) {
  int mt = blockIdx.x;
  int s = blockIdx.y >> 2, ht = blockIdx.y & 3;
  __shared__ unsigned short sA[64 * 40];
  __shared__ unsigned short sB[512 * 40];
  int tid = threadIdx.x, lane = tid & 63, wid = tid >> 6;
  int wr = wid >> 1, wc = wid & 1;
  f32x4 zero = {0.f, 0.f, 0.f, 0.f};
  f32x4 acc[16];
#pragma unroll
  for (int f = 0; f < 16; f++) acc[f] = zero;

  for (int k0 = 0; k0 < DDIM; k0 += 32) {
    {
      int r = tid >> 3, l8 = tid & 7;
      int tok = mt * 64 + r;
      us4 v = *reinterpret_cast<const us4*>(xb + tok * DDIM + k0 + l8 * 4);
      *reinterpret_cast<us4*>(sA + r * 40 + l8 * 4) = v;
    }
    {
      int rr = tid >> 2, l4 = tid & 3;
#pragma unroll
      for (int p = 0; p < 4; p++) {
        int c = rr + p * 128;
        int sel = (c >> 7) & 1;
        int hl = ((c >> 8) << 7) | (c & 127);
        int h = ht * 256 + hl;
        const unsigned short* Wb = sel ? Sub : Sgb;
        us8 v = *reinterpret_cast<const us8*>(Wb + (s * HSH + h) * DDIM + k0 + l4 * 8);
        *reinterpret_cast<us8*>(sB + c * 40 + l4 * 8) = v;
      }
    }
    __syncthreads();
    int ka = (lane >> 4) * 8;
    bf16x8 a = *reinterpret_cast<const bf16x8*>(sA + (wr * 16 + (lane & 15)) * 40 + ka);
#pragma unroll
    for (int f = 0; f < 16; f++) {
      bf16x8 b = *reinterpret_cast<const bf16x8*>(sB + (wc * 256 + f * 16 + (lane & 15)) * 40 + ka);
      acc[f] = __builtin_amdgcn_mfma_f32_16x16x32_bf16(a, b, acc[f], 0, 0, 0);
    }
    __syncthreads();
  }
#pragma unroll
  for (int f = 0; f < 8; f++) {
#pragma unroll
    for (int r = 0; r < 4; r++) {
      int tl = wr * 16 + (lane >> 4) * 4 + r;
      int tok = mt * 64 + tl;
      float g = acc[f][r], u = acc[f + 8][r];
      float hval = (g / (1.f + __expf(-g))) * u;
      int h = ht * 256 + wc * 128 + f * 16 + (lane & 15);
      hs[(tok * NSH + s) * HSH + h] = f2bf(hval);
    }
  }
}

// ---------------- shared down-proj (accumulate over s, RMW add onto routed out) ----------------
__global__ __launch_bounds__(512) void k_shared_down(const unsigned short* __restrict__ hs,
                                                     const unsigned short* __restrict__ Sdb,
                                                     float* __restrict__ out) {
  int mt = blockIdx.x, dh = blockIdx.y;
  __shared__ unsigned short sA[64 * 40];
  __shared__ unsigned short sB[512 * 40];
  int tid = threadIdx.x, lane = tid & 63, wid = tid >> 6;
  int wr = wid >> 1, wc = wid & 1;
  f32x4 zero = {0.f, 0.f, 0.f, 0.f};
  f32x4 acc[16];
#pragma unroll
  for (int f = 0; f < 16; f++) acc[f] = zero;

  for (int s = 0; s < NSH; s++) {
    for (int k0 = 0; k0 < HSH; k0 += 32) {
      {
        int r = tid >> 3, l8 = tid & 7;
        int tok = mt * 64 + r;
        us4 v = *reinterpret_cast<const us4*>(hs + (tok * NSH + s) * HSH + k0 + l8 * 4);
        *reinterpret_cast<us4*>(sA + r * 40 + l8 * 4) = v;
      }
      {
        int rr = tid >> 2, l4 = tid & 3;
#pragma unroll
        for (int p = 0; p < 4; p++) {
          int c = rr + p * 128;
          int d = dh * 512 + c;
          us8 v = *reinterpret_cast<const us8*>(Sdb + (s * DDIM + d) * HSH + k0 + l4 * 8);
          *reinterpret_cast<us8*>(sB + c * 40 + l4 * 8) = v;
        }
      }
      __syncthreads();
      int ka = (lane >> 4) * 8;
      bf16x8 a = *reinterpret_cast<const bf16x8*>(sA + (wr * 16 + (lane & 15)) * 40 + ka);
#pragma unroll
      for (int f = 0; f < 16; f++) {
        bf16x8 b = *reinterpret_cast<const bf16x8*>(sB + (wc * 256 + f * 16 + (lane & 15)) * 40 + ka);
        acc[f] = __builtin_amdgcn_mfma_f32_16x16x32_bf16(a, b, acc[f], 0, 0, 0);
      }
      __syncthreads();
    }
  }
#pragma unroll
  for (int f = 0; f < 16; f++) {
#pragma unroll
    for (int r = 0; r < 4; r++) {
      int tl = wr * 16 + (lane >> 4) * 4 + r;
      int tok = mt * 64 + tl;
      int d = dh * 512 + wc * 256 + f * 16 + (lane & 15);
      int o = tok * DDIM + d;
      out[o] = out[o] + acc[f][r];   // single writer per element; runs after routed_down
    }
  }
}

extern "C" void kernel_launch(void* const* d_in, const int* in_sizes, int n_in,
                              void* d_out, int out_size, void* d_ws, size_t ws_size,
                              hipStream_t stream) {
  const float* x  = (const float*)d_in[0];
  const float* Wr = (const float*)d_in[1];
  const float* rb = (const float*)d_in[2];
  const float* Wg = (const float*)d_in[3];
  const float* Wu = (const float*)d_in[4];
  const float* Wd = (const float*)d_in[5];
  const float* Sg = (const float*)d_in[6];
  const float* Su = (const float*)d_in[7];
  const float* Sd = (const float*)d_in[8];
  float* out = (float*)d_out;
  char* w = (char*)d_ws;

  unsigned short* xb  = (unsigned short*)(w + (size_t)0);
  unsigned short* Wgb = (unsigned short*)(w + ((size_t)4  << 20));
  unsigned short* Wub = (unsigned short*)(w + ((size_t)20 << 20));
  unsigned short* Wdb = (unsigned short*)(w + ((size_t)36 << 20));
  unsigned short* Sgb = (unsigned short*)(w + ((size_t)52 << 20));
  unsigned short* Sub = (unsigned short*)(w + ((size_t)56 << 20));
  unsigned short* Sdb = (unsigned short*)(w + ((size_t)60 << 20));
  unsigned short* hw  = (unsigned short*)(w + ((size_t)64 << 20));
  unsigned short* hs  = (unsigned short*)(w + ((size_t)68 << 20));
  int*   cnt = (int*)(w + ((size_t)76 << 20));
  int*   ent = (int*)(w + ((size_t)76 << 20) + 4096);
  float* wgt = (float*)(w + ((size_t)76 << 20) + 4096 + (size_t)NEXP * N_TOK * 4);

  hipMemsetAsync(cnt, 0, NEXP * sizeof(int), stream);
  hipMemsetAsync(out, 0, (size_t)out_size * sizeof(float), stream);

  // fp32 -> bf16 conversions
  {
    int n4;
    n4 = N_TOK * DDIM / 4;          k_cvt<<<(n4 + 255) / 256, 256, 0, stream>>>(x,  xb,  n4);
    n4 = NEXP * HDIM * DDIM / 4;    k_cvt<<<(n4 + 255) / 256, 256, 0, stream>>>(Wg, Wgb, n4);
    n4 = NEXP * HDIM * DDIM / 4;    k_cvt<<<(n4 + 255) / 256, 256, 0, stream>>>(Wu, Wub, n4);
    n4 = NEXP * DDIM * HDIM / 4;    k_cvt<<<(n4 + 255) / 256, 256, 0, stream>>>(Wd, Wdb, n4);
    n4 = NSH * HSH * DDIM / 4;      k_cvt<<<(n4 + 255) / 256, 256, 0, stream>>>(Sg, Sgb, n4);
    n4 = NSH * HSH * DDIM / 4;      k_cvt<<<(n4 + 255) / 256, 256, 0, stream>>>(Su, Sub, n4);
    n4 = NSH * DDIM * HSH / 4;      k_cvt<<<(n4 + 255) / 256, 256, 0, stream>>>(Sd, Sdb, n4);
  }

  k_router<<<N_TOK, 256, 0, stream>>>(x, Wr, rb, cnt, ent, wgt);

  k_routed_gu<<<dim3(NEXP, 32), 512, 0, stream>>>(xb, Wgb, Wub, cnt, ent, wgt, hw);
  k_routed_down<<<dim3(NEXP, 32, 2), 512, 0, stream>>>(hw, Wdb, cnt, ent, out);

  k_shared_gu<<<dim3(32, 8), 512, 0, stream>>>(xb, Sgb, Sub, hs);
  k_shared_down<<<dim3(32, 2), 512, 0, stream>>>(hs, Sdb, out);
}

// Round 2
// 345.770 us; speedup vs baseline: 1.0862x; 1.0862x over previous
//
#include <hip/hip_runtime.h>

// MoE FFN: B=2,T=1024,D=1024, E=32,H=256,TOPK=4, S=2,HS=1024. N=2048 tokens.
// bf16 MFMA for FFN GEMMs; fp32 router (exact top-k semantics).
// Round 2: GEMM-style router + padded atomic counters; down-proj scatter via
// per-slot stores (no atomics) + combine folded into shared_down epilogue.

#define N_TOK 2048
#define DDIM 1024
#define NEXP 32
#define HDIM 256
#define TOPK 4
#define NSH 2
#define HSH 1024
#define CNTS 32   // cnt stride in ints (128B padding to kill atomic line contention)

typedef unsigned short us4 __attribute__((ext_vector_type(4)));
typedef unsigned short us8 __attribute__((ext_vector_type(8)));
typedef short bf16x8 __attribute__((ext_vector_type(8)));
typedef float f32x4 __attribute__((ext_vector_type(4)));

__device__ __forceinline__ unsigned short f2bf(float f) {
  union { float f; unsigned u; } v; v.f = f;
  unsigned r = v.u + 0x7fffu + ((v.u >> 16) & 1u);   // RNE
  return (unsigned short)(r >> 16);
}

// ---------------- fp32 -> bf16 conversion ----------------
__global__ void k_cvt(const float* __restrict__ src, unsigned short* __restrict__ dst, int n4) {
  int i = blockIdx.x * 256 + threadIdx.x;
  if (i >= n4) return;
  float4 v = reinterpret_cast<const float4*>(src)[i];
  us4 o;
  o[0] = f2bf(v.x); o[1] = f2bf(v.y); o[2] = f2bf(v.z); o[3] = f2bf(v.w);
  reinterpret_cast<us4*>(dst)[i] = o;
}

// ---------------- router ----------------
// 256 blocks x 256 threads; block = 8 tokens x 32 experts, thread = one (tok,e) dot.
// fp32 exact (matches reference top-k tie semantics). Then 8 threads/block do
// serial top-4 + softmax + list append with 128B-padded atomic counters.
__global__ __launch_bounds__(256) void k_router2(const float* __restrict__ x,
                                                 const float* __restrict__ Wr,
                                                 const float* __restrict__ rb,
                                                 int* __restrict__ cnt,
                                                 int* __restrict__ ent,
                                                 float* __restrict__ wgt) {
  int blk = blockIdx.x;
  __shared__ float sX[8 * 1024];
  __shared__ float sLog[8 * 32];
  int tid = threadIdx.x;
  {
    const float4* xsrc = reinterpret_cast<const float4*>(x + (size_t)blk * 8 * 1024);
    float4* xdst = reinterpret_cast<float4*>(sX);
#pragma unroll
    for (int i = 0; i < 8; i++) xdst[tid + 256 * i] = xsrc[tid + 256 * i];
  }
  __syncthreads();
  int tloc = tid >> 5, e = tid & 31;
  const float4* wr4 = reinterpret_cast<const float4*>(Wr + e * DDIM);
  const float* xr = sX + tloc * 1024;
  float acc = 0.f;
#pragma unroll 8
  for (int d4 = 0; d4 < 256; d4++) {
    float4 wv = wr4[d4];
    acc += xr[d4 * 4 + 0] * wv.x + xr[d4 * 4 + 1] * wv.y +
           xr[d4 * 4 + 2] * wv.z + xr[d4 * 4 + 3] * wv.w;
  }
  sLog[tloc * 32 + e] = acc;
  __syncthreads();
  if (tid < 8) {
    int tok = blk * 8 + tid;
    const float* lg = sLog + tid * 32;
    int usedmask = 0;
    int idx[TOPK]; float lv[TOPK];
#pragma unroll
    for (int k = 0; k < TOPK; k++) {
      float best = -3.4e38f; int bi = 0;
      for (int ee = 0; ee < NEXP; ee++) {
        if ((usedmask >> ee) & 1) continue;
        float v = lg[ee] + rb[ee];
        if (v > best) { best = v; bi = ee; }
      }
      usedmask |= 1 << bi; idx[k] = bi; lv[k] = lg[bi];
    }
    float m = fmaxf(fmaxf(lv[0], lv[1]), fmaxf(lv[2], lv[3]));
    float w[TOPK]; float ssum = 0.f;
#pragma unroll
    for (int k = 0; k < TOPK; k++) { w[k] = __expf(lv[k] - m); ssum += w[k]; }
    float inv = 1.f / ssum;
#pragma unroll
    for (int k = 0; k < TOPK; k++) {
      int ee = idx[k];
      int pos = atomicAdd(&cnt[ee * CNTS], 1);
      ent[ee * N_TOK + pos] = tok * TOPK + k;
      wgt[ee * N_TOK + pos] = w[k] * inv;
    }
  }
}

// ---------------- routed gate+up (+swiglu) ----------------
__global__ __launch_bounds__(512) void k_routed_gu(const unsigned short* __restrict__ xb,
                                                   const unsigned short* __restrict__ Wgb,
                                                   const unsigned short* __restrict__ Wub,
                                                   const int* __restrict__ cnt,
                                                   const int* __restrict__ ent,
                                                   const float* __restrict__ wgt,
                                                   unsigned short* __restrict__ hw) {
  int e = blockIdx.x, tile = blockIdx.y;
  int ne = cnt[e * CNTS];
  if (tile * 64 >= ne) return;
  __shared__ unsigned short sA[64 * 40];
  __shared__ unsigned short sB[512 * 40];
  __shared__ int sTok[64];
  __shared__ float sW[64];
  int tid = threadIdx.x, lane = tid & 63, wid = tid >> 6;
  int wr = wid >> 1, wc = wid & 1;
  if (tid < 64) {
    int pos = tile * 64 + tid;
    int p2 = min(pos, ne - 1);
    sTok[tid] = ent[e * N_TOK + p2];
    sW[tid] = (pos < ne) ? wgt[e * N_TOK + p2] : 0.f;
  }
  __syncthreads();
  f32x4 zero = {0.f, 0.f, 0.f, 0.f};
  f32x4 acc[16];
#pragma unroll
  for (int f = 0; f < 16; f++) acc[f] = zero;

  for (int k0 = 0; k0 < DDIM; k0 += 32) {
    {
      int r = tid >> 3, l8 = tid & 7;
      int tok = sTok[r] >> 2;
      us4 v = *reinterpret_cast<const us4*>(xb + tok * DDIM + k0 + l8 * 4);
      *reinterpret_cast<us4*>(sA + r * 40 + l8 * 4) = v;
    }
    {
      int rr = tid >> 2, l4 = tid & 3;
#pragma unroll
      for (int p = 0; p < 4; p++) {
        int c = rr + p * 128;
        int sel = (c >> 7) & 1;
        int h = ((c >> 8) << 7) | (c & 127);
        const unsigned short* Wb = sel ? Wub : Wgb;
        us8 v = *reinterpret_cast<const us8*>(Wb + (e * HDIM + h) * DDIM + k0 + l4 * 8);
        *reinterpret_cast<us8*>(sB + c * 40 + l4 * 8) = v;
      }
    }
    __syncthreads();
    int ka = (lane >> 4) * 8;
    bf16x8 a = *reinterpret_cast<const bf16x8*>(sA + (wr * 16 + (lane & 15)) * 40 + ka);
#pragma unroll
    for (int f = 0; f < 16; f++) {
      bf16x8 b = *reinterpret_cast<const bf16x8*>(sB + (wc * 256 + f * 16 + (lane & 15)) * 40 + ka);
      acc[f] = __builtin_amdgcn_mfma_f32_16x16x32_bf16(a, b, acc[f], 0, 0, 0);
    }
    __syncthreads();
  }
#pragma unroll
  for (int f = 0; f < 8; f++) {
#pragma unroll
    for (int r = 0; r < 4; r++) {
      int tl = wr * 16 + (lane >> 4) * 4 + r;
      int pos = tile * 64 + tl;
      if (pos < ne) {
        float g = acc[f][r], u = acc[f + 8][r];
        float w = sW[tl];
        float hval = (g / (1.f + __expf(-g))) * u * w;
        int ts = sTok[tl];
        int hcol = wc * 128 + f * 16 + (lane & 15);
        hw[ts * HDIM + hcol] = f2bf(hval);
      }
    }
  }
}

// ---------------- routed down-proj (per-slot store, no atomics) ----------------
__global__ __launch_bounds__(512) void k_routed_down(const unsigned short* __restrict__ hw,
                                                     const unsigned short* __restrict__ Wdb,
                                                     const int* __restrict__ cnt,
                                                     const int* __restrict__ ent,
                                                     float* __restrict__ Pslot) {
  int e = blockIdx.x, tile = blockIdx.y, dh = blockIdx.z;
  int ne = cnt[e * CNTS];
  if (tile * 64 >= ne) return;
  __shared__ unsigned short sA[64 * 40];
  __shared__ unsigned short sB[512 * 40];
  __shared__ int sTok[64];
  int tid = threadIdx.x, lane = tid & 63, wid = tid >> 6;
  int wr = wid >> 1, wc = wid & 1;
  if (tid < 64) {
    int pos = tile * 64 + tid;
    int p2 = min(pos, ne - 1);
    sTok[tid] = ent[e * N_TOK + p2];
  }
  __syncthreads();
  f32x4 zero = {0.f, 0.f, 0.f, 0.f};
  f32x4 acc[16];
#pragma unroll
  for (int f = 0; f < 16; f++) acc[f] = zero;

  for (int k0 = 0; k0 < HDIM; k0 += 32) {
    {
      int r = tid >> 3, l8 = tid & 7;
      int row = sTok[r];
      us4 v = *reinterpret_cast<const us4*>(hw + row * HDIM + k0 + l8 * 4);
      *reinterpret_cast<us4*>(sA + r * 40 + l8 * 4) = v;
    }
    {
      int rr = tid >> 2, l4 = tid & 3;
#pragma unroll
      for (int p = 0; p < 4; p++) {
        int c = rr + p * 128;
        int d = dh * 512 + c;
        us8 v = *reinterpret_cast<const us8*>(Wdb + (e * DDIM + d) * HDIM + k0 + l4 * 8);
        *reinterpret_cast<us8*>(sB + c * 40 + l4 * 8) = v;
      }
    }
    __syncthreads();
    int ka = (lane >> 4) * 8;
    bf16x8 a = *reinterpret_cast<const bf16x8*>(sA + (wr * 16 + (lane & 15)) * 40 + ka);
#pragma unroll
    for (int f = 0; f < 16; f++) {
      bf16x8 b = *reinterpret_cast<const bf16x8*>(sB + (wc * 256 + f * 16 + (lane & 15)) * 40 + ka);
      acc[f] = __builtin_amdgcn_mfma_f32_16x16x32_bf16(a, b, acc[f], 0, 0, 0);
    }
    __syncthreads();
  }
#pragma unroll
  for (int f = 0; f < 16; f++) {
#pragma unroll
    for (int r = 0; r < 4; r++) {
      int tl = wr * 16 + (lane >> 4) * 4 + r;
      int pos = tile * 64 + tl;
      if (pos < ne) {
        int ts = sTok[tl];
        int d = dh * 512 + wc * 256 + f * 16 + (lane & 15);
        Pslot[(size_t)ts * DDIM + d] = acc[f][r];
      }
    }
  }
}

// ---------------- shared gate+up (+swiglu) ----------------
__global__ __launch_bounds__(512) void k_shared_gu(const unsigned short* __restrict__ xb,
                                                   const unsigned short* __restrict__ Sgb,
                                                   const unsigned short* __restrict__ Sub,
                                                   unsigned short* __restrict__ hs) {
  int mt = blockIdx.x;
  int s = blockIdx.y >> 2, ht = blockIdx.y & 3;
  __shared__ unsigned short sA[64 * 40];
  __shared__ unsigned short sB[512 * 40];
  int tid = threadIdx.x, lane = tid & 63, wid = tid >> 6;
  int wr = wid >> 1, wc = wid & 1;
  f32x4 zero = {0.f, 0.f, 0.f, 0.f};
  f32x4 acc[16];
#pragma unroll
  for (int f = 0; f < 16; f++) acc[f] = zero;

  for (int k0 = 0; k0 < DDIM; k0 += 32) {
    {
      int r = tid >> 3, l8 = tid & 7;
      int tok = mt * 64 + r;
      us4 v = *reinterpret_cast<const us4*>(xb + tok * DDIM + k0 + l8 * 4);
      *reinterpret_cast<us4*>(sA + r * 40 + l8 * 4) = v;
    }
    {
      int rr = tid >> 2, l4 = tid & 3;
#pragma unroll
      for (int p = 0; p < 4; p++) {
        int c = rr + p * 128;
        int sel = (c >> 7) & 1;
        int hl = ((c >> 8) << 7) | (c & 127);
        int h = ht * 256 + hl;
        const unsigned short* Wb = sel ? Sub : Sgb;
        us8 v = *reinterpret_cast<const us8*>(Wb + (s * HSH + h) * DDIM + k0 + l4 * 8);
        *reinterpret_cast<us8*>(sB + c * 40 + l4 * 8) = v;
      }
    }
    __syncthreads();
    int ka = (lane >> 4) * 8;
    bf16x8 a = *reinterpret_cast<const bf16x8*>(sA + (wr * 16 + (lane & 15)) * 40 + ka);
#pragma unroll
    for (int f = 0; f < 16; f++) {
      bf16x8 b = *reinterpret_cast<const bf16x8*>(sB + (wc * 256 + f * 16 + (lane & 15)) * 40 + ka);
      acc[f] = __builtin_amdgcn_mfma_f32_16x16x32_bf16(a, b, acc[f], 0, 0, 0);
    }
    __syncthreads();
  }
#pragma unroll
  for (int f = 0; f < 8; f++) {
#pragma unroll
    for (int r = 0; r < 4; r++) {
      int tl = wr * 16 + (lane >> 4) * 4 + r;
      int tok = mt * 64 + tl;
      float g = acc[f][r], u = acc[f + 8][r];
      float hval = (g / (1.f + __expf(-g))) * u;
      int h = ht * 256 + wc * 128 + f * 16 + (lane & 15);
      hs[(tok * NSH + s) * HSH + h] = f2bf(hval);
    }
  }
}

// ---------------- shared down-proj + final combine (out = shared + sum of 4 routed slots) ----------------
__global__ __launch_bounds__(512) void k_shared_down(const unsigned short* __restrict__ hs,
                                                     const unsigned short* __restrict__ Sdb,
                                                     const float* __restrict__ Pslot,
                                                     float* __restrict__ out) {
  int mt = blockIdx.x, dh = blockIdx.y;
  __shared__ unsigned short sA[64 * 40];
  __shared__ unsigned short sB[512 * 40];
  int tid = threadIdx.x, lane = tid & 63, wid = tid >> 6;
  int wr = wid >> 1, wc = wid & 1;
  f32x4 zero = {0.f, 0.f, 0.f, 0.f};
  f32x4 acc[16];
#pragma unroll
  for (int f = 0; f < 16; f++) acc[f] = zero;

  for (int s = 0; s < NSH; s++) {
    for (int k0 = 0; k0 < HSH; k0 += 32) {
      {
        int r = tid >> 3, l8 = tid & 7;
        int tok = mt * 64 + r;
        us4 v = *reinterpret_cast<const us4*>(hs + (tok * NSH + s) * HSH + k0 + l8 * 4);
        *reinterpret_cast<us4*>(sA + r * 40 + l8 * 4) = v;
      }
      {
        int rr = tid >> 2, l4 = tid & 3;
#pragma unroll
        for (int p = 0; p < 4; p++) {
          int c = rr + p * 128;
          int d = dh * 512 + c;
          us8 v = *reinterpret_cast<const us8*>(Sdb + (s * DDIM + d) * HSH + k0 + l4 * 8);
          *reinterpret_cast<us8*>(sB + c * 40 + l4 * 8) = v;
        }
      }
      __syncthreads();
      int ka = (lane >> 4) * 8;
      bf16x8 a = *reinterpret_cast<const bf16x8*>(sA + (wr * 16 + (lane & 15)) * 40 + ka);
#pragma unroll
      for (int f = 0; f < 16; f++) {
        bf16x8 b = *reinterpret_cast<const bf16x8*>(sB + (wc * 256 + f * 16 + (lane & 15)) * 40 + ka);
        acc[f] = __builtin_amdgcn_mfma_f32_16x16x32_bf16(a, b, acc[f], 0, 0, 0);
      }
      __syncthreads();
    }
  }
#pragma unroll
  for (int f = 0; f < 16; f++) {
#pragma unroll
    for (int r = 0; r < 4; r++) {
      int tl = wr * 16 + (lane >> 4) * 4 + r;
      int tok = mt * 64 + tl;
      int d = dh * 512 + wc * 256 + f * 16 + (lane & 15);
      size_t base = (size_t)(tok * 4) * DDIM + d;
      float s = acc[f][r] + Pslot[base] + Pslot[base + DDIM] +
                Pslot[base + 2 * DDIM] + Pslot[base + 3 * DDIM];
      out[tok * DDIM + d] = s;
    }
  }
}

extern "C" void kernel_launch(void* const* d_in, const int* in_sizes, int n_in,
                              void* d_out, int out_size, void* d_ws, size_t ws_size,
                              hipStream_t stream) {
  const float* x  = (const float*)d_in[0];
  const float* Wr = (const float*)d_in[1];
  const float* rb = (const float*)d_in[2];
  const float* Wg = (const float*)d_in[3];
  const float* Wu = (const float*)d_in[4];
  const float* Wd = (const float*)d_in[5];
  const float* Sg = (const float*)d_in[6];
  const float* Su = (const float*)d_in[7];
  const float* Sd = (const float*)d_in[8];
  float* out = (float*)d_out;
  char* w = (char*)d_ws;

  unsigned short* xb  = (unsigned short*)(w + (size_t)0);
  unsigned short* Wgb = (unsigned short*)(w + ((size_t)4  << 20));
  unsigned short* Wub = (unsigned short*)(w + ((size_t)20 << 20));
  unsigned short* Wdb = (unsigned short*)(w + ((size_t)36 << 20));
  unsigned short* Sgb = (unsigned short*)(w + ((size_t)52 << 20));
  unsigned short* Sub = (unsigned short*)(w + ((size_t)56 << 20));
  unsigned short* Sdb = (unsigned short*)(w + ((size_t)60 << 20));
  unsigned short* hw  = (unsigned short*)(w + ((size_t)64 << 20));
  unsigned short* hs  = (unsigned short*)(w + ((size_t)68 << 20));
  int*   cnt = (int*)(w + ((size_t)76 << 20));
  int*   ent = (int*)(w + ((size_t)76 << 20) + 8192);
  float* wgt = (float*)(w + ((size_t)76 << 20) + 8192 + (size_t)NEXP * N_TOK * 4);
  float* Pslot = (float*)(w + ((size_t)80 << 20));   // 8192 x 1024 f32 = 32MB

  hipMemsetAsync(cnt, 0, NEXP * CNTS * sizeof(int), stream);

  {
    int n4;
    n4 = N_TOK * DDIM / 4;          k_cvt<<<(n4 + 255) / 256, 256, 0, stream>>>(x,  xb,  n4);
    n4 = NEXP * HDIM * DDIM / 4;    k_cvt<<<(n4 + 255) / 256, 256, 0, stream>>>(Wg, Wgb, n4);
    n4 = NEXP * HDIM * DDIM / 4;    k_cvt<<<(n4 + 255) / 256, 256, 0, stream>>>(Wu, Wub, n4);
    n4 = NEXP * DDIM * HDIM / 4;    k_cvt<<<(n4 + 255) / 256, 256, 0, stream>>>(Wd, Wdb, n4);
    n4 = NSH * HSH * DDIM / 4;      k_cvt<<<(n4 + 255) / 256, 256, 0, stream>>>(Sg, Sgb, n4);
    n4 = NSH * HSH * DDIM / 4;      k_cvt<<<(n4 + 255) / 256, 256, 0, stream>>>(Su, Sub, n4);
    n4 = NSH * DDIM * HSH / 4;      k_cvt<<<(n4 + 255) / 256, 256, 0, stream>>>(Sd, Sdb, n4);
  }

  k_router2<<<N_TOK / 8, 256, 0, stream>>>(x, Wr, rb, cnt, ent, wgt);

  k_routed_gu<<<dim3(NEXP, 32), 512, 0, stream>>>(xb, Wgb, Wub, cnt, ent, wgt, hw);
  k_routed_down<<<dim3(NEXP, 32, 2), 512, 0, stream>>>(hw, Wdb, cnt, ent, Pslot);

  k_shared_gu<<<dim3(32, 8), 512, 0, stream>>>(xb, Sgb, Sub, hs);
  k_shared_down<<<dim3(32, 2), 512, 0, stream>>>(hs, Sdb, Pslot, out);
}

// Round 3
// 239.668 us; speedup vs baseline: 1.5670x; 1.4427x over previous
//
#include <hip/hip_runtime.h>

// MoE FFN: B=2,T=1024,D=1024, E=32,H=256,TOPK=4, S=2,HS=1024. N=2048 tokens.
// Round 3: occupancy fix. All GEMMs use 256-thread (4-wave) blocks, 64x256 tiles,
// >=256 active blocks each. Down-proj partials stored bf16; final combine is a
// dedicated streaming kernel.

#define N_TOK 2048
#define DDIM 1024
#define NEXP 32
#define HDIM 256
#define TOPK 4
#define NSH 2
#define HSH 1024
#define CNTS 32

typedef unsigned short us4 __attribute__((ext_vector_type(4)));
typedef unsigned short us8 __attribute__((ext_vector_type(8)));
typedef short bf16x8 __attribute__((ext_vector_type(8)));
typedef float f32x4 __attribute__((ext_vector_type(4)));

__device__ __forceinline__ unsigned short f2bf(float f) {
  union { float f; unsigned u; } v; v.f = f;
  unsigned r = v.u + 0x7fffu + ((v.u >> 16) & 1u);   // RNE
  return (unsigned short)(r >> 16);
}
__device__ __forceinline__ float bf2f(unsigned short h) {
  union { unsigned u; float f; } v; v.u = ((unsigned)h) << 16; return v.f;
}

// ---------------- fp32 -> bf16 conversion ----------------
__global__ void k_cvt(const float* __restrict__ src, unsigned short* __restrict__ dst, int n4) {
  int i = blockIdx.x * 256 + threadIdx.x;
  if (i >= n4) return;
  float4 v = reinterpret_cast<const float4*>(src)[i];
  us4 o;
  o[0] = f2bf(v.x); o[1] = f2bf(v.y); o[2] = f2bf(v.z); o[3] = f2bf(v.w);
  reinterpret_cast<us4*>(dst)[i] = o;
}

// ---------------- router ----------------
__global__ __launch_bounds__(256) void k_router2(const float* __restrict__ x,
                                                 const float* __restrict__ Wr,
                                                 const float* __restrict__ rb,
                                                 int* __restrict__ cnt,
                                                 int* __restrict__ ent,
                                                 float* __restrict__ wgt) {
  int blk = blockIdx.x;
  __shared__ float sX[8 * 1024];
  __shared__ float sLog[8 * 32];
  int tid = threadIdx.x;
  {
    const float4* xsrc = reinterpret_cast<const float4*>(x + (size_t)blk * 8 * 1024);
    float4* xdst = reinterpret_cast<float4*>(sX);
#pragma unroll
    for (int i = 0; i < 8; i++) xdst[tid + 256 * i] = xsrc[tid + 256 * i];
  }
  __syncthreads();
  int tloc = tid >> 5, e = tid & 31;
  const float4* wr4 = reinterpret_cast<const float4*>(Wr + e * DDIM);
  const float* xr = sX + tloc * 1024;
  float acc = 0.f;
#pragma unroll 8
  for (int d4 = 0; d4 < 256; d4++) {
    float4 wv = wr4[d4];
    acc += xr[d4 * 4 + 0] * wv.x + xr[d4 * 4 + 1] * wv.y +
           xr[d4 * 4 + 2] * wv.z + xr[d4 * 4 + 3] * wv.w;
  }
  sLog[tloc * 32 + e] = acc;
  __syncthreads();
  if (tid < 8) {
    int tok = blk * 8 + tid;
    const float* lg = sLog + tid * 32;
    int usedmask = 0;
    int idx[TOPK]; float lv[TOPK];
#pragma unroll
    for (int k = 0; k < TOPK; k++) {
      float best = -3.4e38f; int bi = 0;
      for (int ee = 0; ee < NEXP; ee++) {
        if ((usedmask >> ee) & 1) continue;
        float v = lg[ee] + rb[ee];
        if (v > best) { best = v; bi = ee; }
      }
      usedmask |= 1 << bi; idx[k] = bi; lv[k] = lg[bi];
    }
    float m = fmaxf(fmaxf(lv[0], lv[1]), fmaxf(lv[2], lv[3]));
    float w[TOPK]; float ssum = 0.f;
#pragma unroll
    for (int k = 0; k < TOPK; k++) { w[k] = __expf(lv[k] - m); ssum += w[k]; }
    float inv = 1.f / ssum;
#pragma unroll
    for (int k = 0; k < TOPK; k++) {
      int ee = idx[k];
      int pos = atomicAdd(&cnt[ee * CNTS], 1);
      ent[ee * N_TOK + pos] = tok * TOPK + k;
      wgt[ee * N_TOK + pos] = w[k] * inv;
    }
  }
}

// ---------------- routed gate+up (+swiglu) ----------------
// grid (e, mt, ht). 256 thr / 4 waves. tile 64 rows x 256 cols (128 g + 128 u).
__global__ __launch_bounds__(256) void k_routed_gu(const unsigned short* __restrict__ xb,
                                                   const unsigned short* __restrict__ Wgb,
                                                   const unsigned short* __restrict__ Wub,
                                                   const int* __restrict__ cnt,
                                                   const int* __restrict__ ent,
                                                   const float* __restrict__ wgt,
                                                   unsigned short* __restrict__ hw) {
  int e = blockIdx.x, mt = blockIdx.y, ht = blockIdx.z;
  int ne = cnt[e * CNTS];
  if (mt * 64 >= ne) return;
  __shared__ unsigned short sA[64 * 40];
  __shared__ unsigned short sB[256 * 40];
  __shared__ int sTok[64];
  __shared__ float sW[64];
  int tid = threadIdx.x, lane = tid & 63, w = tid >> 6;
  if (tid < 64) {
    int pos = mt * 64 + tid;
    int p2 = min(pos, ne - 1);
    sTok[tid] = ent[e * N_TOK + p2];
    sW[tid] = (pos < ne) ? wgt[e * N_TOK + p2] : 0.f;
  }
  __syncthreads();
  int ar = tid >> 2, l4 = tid & 3;
  const unsigned short* aSrc = xb + (size_t)(sTok[ar] >> 2) * DDIM + l4 * 8;
  const unsigned short* bSrc[4];
#pragma unroll
  for (int p = 0; p < 4; p++) {
    int c = ar + p * 64;
    int sel = (c >> 7) & 1;
    int h = ht * 128 + (c & 127);
    bSrc[p] = (sel ? Wub : Wgb) + (size_t)(e * HDIM + h) * DDIM + l4 * 8;
  }
  f32x4 zero = {0.f, 0.f, 0.f, 0.f};
  f32x4 acc[16];
#pragma unroll
  for (int f = 0; f < 16; f++) acc[f] = zero;

  for (int k0 = 0; k0 < DDIM; k0 += 32) {
    *reinterpret_cast<us8*>(sA + ar * 40 + l4 * 8) = *reinterpret_cast<const us8*>(aSrc + k0);
#pragma unroll
    for (int p = 0; p < 4; p++)
      *reinterpret_cast<us8*>(sB + (ar + p * 64) * 40 + l4 * 8) = *reinterpret_cast<const us8*>(bSrc[p] + k0);
    __syncthreads();
    int ka = (lane >> 4) * 8;
    bf16x8 a = *reinterpret_cast<const bf16x8*>(sA + (w * 16 + (lane & 15)) * 40 + ka);
#pragma unroll
    for (int f = 0; f < 16; f++) {
      bf16x8 b = *reinterpret_cast<const bf16x8*>(sB + (f * 16 + (lane & 15)) * 40 + ka);
      acc[f] = __builtin_amdgcn_mfma_f32_16x16x32_bf16(a, b, acc[f], 0, 0, 0);
    }
    __syncthreads();
  }
#pragma unroll
  for (int f = 0; f < 8; f++) {
#pragma unroll
    for (int r = 0; r < 4; r++) {
      int tl = w * 16 + (lane >> 4) * 4 + r;
      int pos = mt * 64 + tl;
      if (pos < ne) {
        float g = acc[f][r], u = acc[f + 8][r];
        float hval = (g / (1.f + __expf(-g))) * u * sW[tl];
        int ts = sTok[tl];
        int h = ht * 128 + f * 16 + (lane & 15);
        hw[(size_t)ts * HDIM + h] = f2bf(hval);
      }
    }
  }
}

// ---------------- routed down-proj (bf16 per-slot store) ----------------
// grid (e, mt, dh 0..3). tile 64 rows x 256 cols, K=256.
__global__ __launch_bounds__(256) void k_routed_down(const unsigned short* __restrict__ hw,
                                                     const unsigned short* __restrict__ Wdb,
                                                     const int* __restrict__ cnt,
                                                     const int* __restrict__ ent,
                                                     unsigned short* __restrict__ Pslot) {
  int e = blockIdx.x, mt = blockIdx.y, dh = blockIdx.z;
  int ne = cnt[e * CNTS];
  if (mt * 64 >= ne) return;
  __shared__ unsigned short sA[64 * 40];
  __shared__ unsigned short sB[256 * 40];
  __shared__ int sTok[64];
  int tid = threadIdx.x, lane = tid & 63, w = tid >> 6;
  if (tid < 64) {
    int pos = mt * 64 + tid;
    int p2 = min(pos, ne - 1);
    sTok[tid] = ent[e * N_TOK + p2];
  }
  __syncthreads();
  int ar = tid >> 2, l4 = tid & 3;
  const unsigned short* aSrc = hw + (size_t)sTok[ar] * HDIM + l4 * 8;
  const unsigned short* bSrc[4];
#pragma unroll
  for (int p = 0; p < 4; p++) {
    int d = dh * 256 + ar + p * 64;
    bSrc[p] = Wdb + (size_t)(e * DDIM + d) * HDIM + l4 * 8;
  }
  f32x4 zero = {0.f, 0.f, 0.f, 0.f};
  f32x4 acc[16];
#pragma unroll
  for (int f = 0; f < 16; f++) acc[f] = zero;

  for (int k0 = 0; k0 < HDIM; k0 += 32) {
    *reinterpret_cast<us8*>(sA + ar * 40 + l4 * 8) = *reinterpret_cast<const us8*>(aSrc + k0);
#pragma unroll
    for (int p = 0; p < 4; p++)
      *reinterpret_cast<us8*>(sB + (ar + p * 64) * 40 + l4 * 8) = *reinterpret_cast<const us8*>(bSrc[p] + k0);
    __syncthreads();
    int ka = (lane >> 4) * 8;
    bf16x8 a = *reinterpret_cast<const bf16x8*>(sA + (w * 16 + (lane & 15)) * 40 + ka);
#pragma unroll
    for (int f = 0; f < 16; f++) {
      bf16x8 b = *reinterpret_cast<const bf16x8*>(sB + (f * 16 + (lane & 15)) * 40 + ka);
      acc[f] = __builtin_amdgcn_mfma_f32_16x16x32_bf16(a, b, acc[f], 0, 0, 0);
    }
    __syncthreads();
  }
#pragma unroll
  for (int f = 0; f < 16; f++) {
#pragma unroll
    for (int r = 0; r < 4; r++) {
      int tl = w * 16 + (lane >> 4) * 4 + r;
      int pos = mt * 64 + tl;
      if (pos < ne) {
        int ts = sTok[tl];
        int d = dh * 256 + f * 16 + (lane & 15);
        Pslot[(size_t)ts * DDIM + d] = f2bf(acc[f][r]);
      }
    }
  }
}

// ---------------- shared gate+up (+swiglu) ----------------
// grid (mt, y=s*8+ht). tile 64 rows x 256 cols (128 g + 128 u), K=1024.
__global__ __launch_bounds__(256) void k_shared_gu(const unsigned short* __restrict__ xb,
                                                   const unsigned short* __restrict__ Sgb,
                                                   const unsigned short* __restrict__ Sub,
                                                   unsigned short* __restrict__ hs) {
  int mt = blockIdx.x;
  int s = blockIdx.y >> 3, ht = blockIdx.y & 7;
  __shared__ unsigned short sA[64 * 40];
  __shared__ unsigned short sB[256 * 40];
  int tid = threadIdx.x, lane = tid & 63, w = tid >> 6;
  int ar = tid >> 2, l4 = tid & 3;
  const unsigned short* aSrc = xb + (size_t)(mt * 64 + ar) * DDIM + l4 * 8;
  const unsigned short* bSrc[4];
#pragma unroll
  for (int p = 0; p < 4; p++) {
    int c = ar + p * 64;
    int sel = (c >> 7) & 1;
    int h = ht * 128 + (c & 127);
    bSrc[p] = (sel ? Sub : Sgb) + (size_t)(s * HSH + h) * DDIM + l4 * 8;
  }
  f32x4 zero = {0.f, 0.f, 0.f, 0.f};
  f32x4 acc[16];
#pragma unroll
  for (int f = 0; f < 16; f++) acc[f] = zero;

  for (int k0 = 0; k0 < DDIM; k0 += 32) {
    *reinterpret_cast<us8*>(sA + ar * 40 + l4 * 8) = *reinterpret_cast<const us8*>(aSrc + k0);
#pragma unroll
    for (int p = 0; p < 4; p++)
      *reinterpret_cast<us8*>(sB + (ar + p * 64) * 40 + l4 * 8) = *reinterpret_cast<const us8*>(bSrc[p] + k0);
    __syncthreads();
    int ka = (lane >> 4) * 8;
    bf16x8 a = *reinterpret_cast<const bf16x8*>(sA + (w * 16 + (lane & 15)) * 40 + ka);
#pragma unroll
    for (int f = 0; f < 16; f++) {
      bf16x8 b = *reinterpret_cast<const bf16x8*>(sB + (f * 16 + (lane & 15)) * 40 + ka);
      acc[f] = __builtin_amdgcn_mfma_f32_16x16x32_bf16(a, b, acc[f], 0, 0, 0);
    }
    __syncthreads();
  }
#pragma unroll
  for (int f = 0; f < 8; f++) {
#pragma unroll
    for (int r = 0; r < 4; r++) {
      int tl = w * 16 + (lane >> 4) * 4 + r;
      int tok = mt * 64 + tl;
      float g = acc[f][r], u = acc[f + 8][r];
      float hval = (g / (1.f + __expf(-g))) * u;
      int h = ht * 128 + f * 16 + (lane & 15);
      hs[(size_t)(tok * NSH + s) * HSH + h] = f2bf(hval);
    }
  }
}

// ---------------- shared down-proj (bf16 partial per shared expert) ----------------
// grid (mt, dh 0..3, s 0..1). tile 64 rows x 256 cols, K=1024 (one s).
__global__ __launch_bounds__(256) void k_shared_down(const unsigned short* __restrict__ hs,
                                                     const unsigned short* __restrict__ Sdb,
                                                     unsigned short* __restrict__ Psh) {
  int mt = blockIdx.x, dh = blockIdx.y, s = blockIdx.z;
  __shared__ unsigned short sA[64 * 40];
  __shared__ unsigned short sB[256 * 40];
  int tid = threadIdx.x, lane = tid & 63, w = tid >> 6;
  int ar = tid >> 2, l4 = tid & 3;
  const unsigned short* aSrc = hs + (size_t)((mt * 64 + ar) * NSH + s) * HSH + l4 * 8;
  const unsigned short* bSrc[4];
#pragma unroll
  for (int p = 0; p < 4; p++) {
    int d = dh * 256 + ar + p * 64;
    bSrc[p] = Sdb + (size_t)(s * DDIM + d) * HSH + l4 * 8;
  }
  f32x4 zero = {0.f, 0.f, 0.f, 0.f};
  f32x4 acc[16];
#pragma unroll
  for (int f = 0; f < 16; f++) acc[f] = zero;

  for (int k0 = 0; k0 < HSH; k0 += 32) {
    *reinterpret_cast<us8*>(sA + ar * 40 + l4 * 8) = *reinterpret_cast<const us8*>(aSrc + k0);
#pragma unroll
    for (int p = 0; p < 4; p++)
      *reinterpret_cast<us8*>(sB + (ar + p * 64) * 40 + l4 * 8) = *reinterpret_cast<const us8*>(bSrc[p] + k0);
    __syncthreads();
    int ka = (lane >> 4) * 8;
    bf16x8 a = *reinterpret_cast<const bf16x8*>(sA + (w * 16 + (lane & 15)) * 40 + ka);
#pragma unroll
    for (int f = 0; f < 16; f++) {
      bf16x8 b = *reinterpret_cast<const bf16x8*>(sB + (f * 16 + (lane & 15)) * 40 + ka);
      acc[f] = __builtin_amdgcn_mfma_f32_16x16x32_bf16(a, b, acc[f], 0, 0, 0);
    }
    __syncthreads();
  }
#pragma unroll
  for (int f = 0; f < 16; f++) {
#pragma unroll
    for (int r = 0; r < 4; r++) {
      int tl = w * 16 + (lane >> 4) * 4 + r;
      int tok = mt * 64 + tl;
      int d = dh * 256 + f * 16 + (lane & 15);
      Psh[(size_t)s * N_TOK * DDIM + (size_t)tok * DDIM + d] = f2bf(acc[f][r]);
    }
  }
}

// ---------------- final combine: out = Psh0 + Psh1 + sum_k Pslot[tok*4+k] ----------------
__global__ __launch_bounds__(256) void k_combine(const unsigned short* __restrict__ Pslot,
                                                 const unsigned short* __restrict__ Psh,
                                                 float* __restrict__ out) {
  int i = blockIdx.x * 256 + threadIdx.x;     // each thread: 8 elements
  int base = i * 8;
  int tok = base >> 10, d = base & 1023;
  const us8 p0 = *reinterpret_cast<const us8*>(Pslot + ((size_t)tok * 4 + 0) * DDIM + d);
  const us8 p1 = *reinterpret_cast<const us8*>(Pslot + ((size_t)tok * 4 + 1) * DDIM + d);
  const us8 p2 = *reinterpret_cast<const us8*>(Pslot + ((size_t)tok * 4 + 2) * DDIM + d);
  const us8 p3 = *reinterpret_cast<const us8*>(Pslot + ((size_t)tok * 4 + 3) * DDIM + d);
  const us8 q0 = *reinterpret_cast<const us8*>(Psh + (size_t)base);
  const us8 q1 = *reinterpret_cast<const us8*>(Psh + (size_t)N_TOK * DDIM + base);
  float o[8];
#pragma unroll
  for (int j = 0; j < 8; j++)
    o[j] = bf2f(p0[j]) + bf2f(p1[j]) + bf2f(p2[j]) + bf2f(p3[j]) + bf2f(q0[j]) + bf2f(q1[j]);
  float4 v0 = {o[0], o[1], o[2], o[3]};
  float4 v1 = {o[4], o[5], o[6], o[7]};
  reinterpret_cast<float4*>(out + base)[0] = v0;
  reinterpret_cast<float4*>(out + base)[1] = v1;
}

extern "C" void kernel_launch(void* const* d_in, const int* in_sizes, int n_in,
                              void* d_out, int out_size, void* d_ws, size_t ws_size,
                              hipStream_t stream) {
  const float* x  = (const float*)d_in[0];
  const float* Wr = (const float*)d_in[1];
  const float* rb = (const float*)d_in[2];
  const float* Wg = (const float*)d_in[3];
  const float* Wu = (const float*)d_in[4];
  const float* Wd = (const float*)d_in[5];
  const float* Sg = (const float*)d_in[6];
  const float* Su = (const float*)d_in[7];
  const float* Sd = (const float*)d_in[8];
  float* out = (float*)d_out;
  char* w = (char*)d_ws;

  unsigned short* xb  = (unsigned short*)(w + (size_t)0);
  unsigned short* Wgb = (unsigned short*)(w + ((size_t)4  << 20));
  unsigned short* Wub = (unsigned short*)(w + ((size_t)20 << 20));
  unsigned short* Wdb = (unsigned short*)(w + ((size_t)36 << 20));
  unsigned short* Sgb = (unsigned short*)(w + ((size_t)52 << 20));
  unsigned short* Sub = (unsigned short*)(w + ((size_t)56 << 20));
  unsigned short* Sdb = (unsigned short*)(w + ((size_t)60 << 20));
  unsigned short* hw  = (unsigned short*)(w + ((size_t)64 << 20));
  unsigned short* hs  = (unsigned short*)(w + ((size_t)68 << 20));
  int*   cnt = (int*)(w + ((size_t)76 << 20));
  int*   ent = (int*)(w + ((size_t)76 << 20) + 8192);
  float* wgt = (float*)(w + ((size_t)76 << 20) + 8192 + (size_t)NEXP * N_TOK * 4);
  unsigned short* Pslot = (unsigned short*)(w + ((size_t)78 << 20));  // 8192x1024 bf16 = 16MB
  unsigned short* Psh   = (unsigned short*)(w + ((size_t)94 << 20));  // 2x2048x1024 bf16 = 8MB

  hipMemsetAsync(cnt, 0, NEXP * CNTS * sizeof(int), stream);

  {
    int n4;
    n4 = N_TOK * DDIM / 4;          k_cvt<<<(n4 + 255) / 256, 256, 0, stream>>>(x,  xb,  n4);
    n4 = NEXP * HDIM * DDIM / 4;    k_cvt<<<(n4 + 255) / 256, 256, 0, stream>>>(Wg, Wgb, n4);
    n4 = NEXP * HDIM * DDIM / 4;    k_cvt<<<(n4 + 255) / 256, 256, 0, stream>>>(Wu, Wub, n4);
    n4 = NEXP * DDIM * HDIM / 4;    k_cvt<<<(n4 + 255) / 256, 256, 0, stream>>>(Wd, Wdb, n4);
    n4 = NSH * HSH * DDIM / 4;      k_cvt<<<(n4 + 255) / 256, 256, 0, stream>>>(Sg, Sgb, n4);
    n4 = NSH * HSH * DDIM / 4;      k_cvt<<<(n4 + 255) / 256, 256, 0, stream>>>(Su, Sub, n4);
    n4 = NSH * DDIM * HSH / 4;      k_cvt<<<(n4 + 255) / 256, 256, 0, stream>>>(Sd, Sdb, n4);
  }

  k_router2<<<N_TOK / 8, 256, 0, stream>>>(x, Wr, rb, cnt, ent, wgt);

  k_routed_gu<<<dim3(NEXP, 32, 2), 256, 0, stream>>>(xb, Wgb, Wub, cnt, ent, wgt, hw);
  k_routed_down<<<dim3(NEXP, 32, 4), 256, 0, stream>>>(hw, Wdb, cnt, ent, Pslot);

  k_shared_gu<<<dim3(32, 16), 256, 0, stream>>>(xb, Sgb, Sub, hs);
  k_shared_down<<<dim3(32, 4, 2), 256, 0, stream>>>(hs, Sdb, Psh);

  k_combine<<<N_TOK * DDIM / (256 * 8), 256, 0, stream>>>(Pslot, Psh, out);
}

// Round 4
// 185.464 us; speedup vs baseline: 2.0250x; 1.2923x over previous
//
#include <hip/hip_runtime.h>

// MoE FFN: B=2,T=1024,D=1024, E=32,H=256,TOPK=4, S=2,HS=1024. N=2048 tokens.
// Round 4: latency fix. (1) fp32 weights loaded directly in GEMM staging
// (bf16 cvt in-register; no weight cvt pass). (2) prefetch-depth-1 pipeline:
// issue next-tile global loads BEFORE a raw s_barrier (loads fly across it),
// double-buffered LDS, one barrier/iter. (3) >=512-block grids for occupancy.

#define N_TOK 2048
#define DDIM 1024
#define NEXP 32
#define HDIM 256
#define TOPK 4
#define NSH 2
#define HSH 1024
#define CNTS 32

typedef unsigned short us4 __attribute__((ext_vector_type(4)));
typedef unsigned short us8 __attribute__((ext_vector_type(8)));
typedef short bf16x8 __attribute__((ext_vector_type(8)));
typedef float f32x4 __attribute__((ext_vector_type(4)));

__device__ __forceinline__ unsigned short f2bf(float f) {
  union { float f; unsigned u; } v; v.f = f;
  unsigned r = v.u + 0x7fffu + ((v.u >> 16) & 1u);   // RNE
  return (unsigned short)(r >> 16);
}
__device__ __forceinline__ float bf2f(unsigned short h) {
  union { unsigned u; float f; } v; v.u = ((unsigned)h) << 16; return v.f;
}
__device__ __forceinline__ us4 cvt4(float4 v) {
  us4 o; o[0] = f2bf(v.x); o[1] = f2bf(v.y); o[2] = f2bf(v.z); o[3] = f2bf(v.w);
  return o;
}

// ---------------- fp32 -> bf16 conversion (x only) ----------------
__global__ void k_cvt(const float* __restrict__ src, unsigned short* __restrict__ dst, int n4) {
  int i = blockIdx.x * 256 + threadIdx.x;
  if (i >= n4) return;
  reinterpret_cast<us4*>(dst)[i] = cvt4(reinterpret_cast<const float4*>(src)[i]);
}

// ---------------- router ----------------
__global__ __launch_bounds__(256) void k_router2(const float* __restrict__ x,
                                                 const float* __restrict__ Wr,
                                                 const float* __restrict__ rb,
                                                 int* __restrict__ cnt,
                                                 int* __restrict__ ent,
                                                 float* __restrict__ wgt) {
  int blk = blockIdx.x;
  __shared__ float sX[8 * 1024];
  __shared__ float sLog[8 * 32];
  int tid = threadIdx.x;
  {
    const float4* xsrc = reinterpret_cast<const float4*>(x + (size_t)blk * 8 * 1024);
    float4* xdst = reinterpret_cast<float4*>(sX);
#pragma unroll
    for (int i = 0; i < 8; i++) xdst[tid + 256 * i] = xsrc[tid + 256 * i];
  }
  __syncthreads();
  int tloc = tid >> 5, e = tid & 31;
  const float4* wr4 = reinterpret_cast<const float4*>(Wr + e * DDIM);
  const float* xr = sX + tloc * 1024;
  float acc = 0.f;
#pragma unroll 8
  for (int d4 = 0; d4 < 256; d4++) {
    float4 wv = wr4[d4];
    acc += xr[d4 * 4 + 0] * wv.x + xr[d4 * 4 + 1] * wv.y +
           xr[d4 * 4 + 2] * wv.z + xr[d4 * 4 + 3] * wv.w;
  }
  sLog[tloc * 32 + e] = acc;
  __syncthreads();
  if (tid < 8) {
    int tok = blk * 8 + tid;
    const float* lg = sLog + tid * 32;
    int usedmask = 0;
    int idx[TOPK]; float lv[TOPK];
#pragma unroll
    for (int k = 0; k < TOPK; k++) {
      float best = -3.4e38f; int bi = 0;
      for (int ee = 0; ee < NEXP; ee++) {
        if ((usedmask >> ee) & 1) continue;
        float v = lg[ee] + rb[ee];
        if (v > best) { best = v; bi = ee; }
      }
      usedmask |= 1 << bi; idx[k] = bi; lv[k] = lg[bi];
    }
    float m = fmaxf(fmaxf(lv[0], lv[1]), fmaxf(lv[2], lv[3]));
    float w[TOPK]; float ssum = 0.f;
#pragma unroll
    for (int k = 0; k < TOPK; k++) { w[k] = __expf(lv[k] - m); ssum += w[k]; }
    float inv = 1.f / ssum;
#pragma unroll
    for (int k = 0; k < TOPK; k++) {
      int ee = idx[k];
      int pos = atomicAdd(&cnt[ee * CNTS], 1);
      ent[ee * N_TOK + pos] = tok * TOPK + k;
      wgt[ee * N_TOK + pos] = w[k] * inv;
    }
  }
}

// ---------------- shared gate+up (+swiglu) ----------------
// grid (mt=32, y=s*8+ht), 256 thr. tile 64 x 256 (128 g | 128 u), K=1024.
__global__ __launch_bounds__(256) void k_shared_gu(const unsigned short* __restrict__ xb,
                                                   const float* __restrict__ Sg,
                                                   const float* __restrict__ Su,
                                                   unsigned short* __restrict__ hs) {
  int mt = blockIdx.x;
  int s = blockIdx.y >> 3, ht = blockIdx.y & 7;
  __shared__ unsigned short sA[2][64 * 40];
  __shared__ unsigned short sB[2][256 * 40];
  int tid = threadIdx.x, lane = tid & 63, w = tid >> 6;

  int arow = tid >> 2, al4 = tid & 3;
  const unsigned short* aSrc = xb + (size_t)(mt * 64 + arow) * DDIM + al4 * 8;
  int br = tid >> 3, bl8 = tid & 7;
  const float* bSrc[8];
#pragma unroll
  for (int p = 0; p < 8; p++) {
    int h = ht * 128 + br + (p & 3) * 32;
    bSrc[p] = ((p >> 2) ? Su : Sg) + (size_t)(s * HSH + h) * DDIM + bl8 * 4;
  }

  us8 aReg = *reinterpret_cast<const us8*>(aSrc);
  float4 bReg[8];
#pragma unroll
  for (int p = 0; p < 8; p++) bReg[p] = *reinterpret_cast<const float4*>(bSrc[p]);

  f32x4 acc[16];
#pragma unroll
  for (int f = 0; f < 16; f++) acc[f] = {0.f, 0.f, 0.f, 0.f};

  int cur = 0;
  for (int step = 0; step < 32; ++step) {
    *reinterpret_cast<us8*>(&sA[cur][arow * 40 + al4 * 8]) = aReg;
#pragma unroll
    for (int p = 0; p < 8; p++) {
      int c = br + p * 32;
      *reinterpret_cast<us4*>(&sB[cur][c * 40 + bl8 * 4]) = cvt4(bReg[p]);
    }
    if (step < 31) {
      int k0 = (step + 1) * 32;
      aReg = *reinterpret_cast<const us8*>(aSrc + k0);
#pragma unroll
      for (int p = 0; p < 8; p++) bReg[p] = *reinterpret_cast<const float4*>(bSrc[p] + k0);
    }
    asm volatile("s_waitcnt lgkmcnt(0)" ::: "memory");
    __builtin_amdgcn_s_barrier();
    int ka = (lane >> 4) * 8;
    bf16x8 a = *reinterpret_cast<const bf16x8*>(&sA[cur][(w * 16 + (lane & 15)) * 40 + ka]);
#pragma unroll
    for (int f = 0; f < 16; f++) {
      bf16x8 b = *reinterpret_cast<const bf16x8*>(&sB[cur][(f * 16 + (lane & 15)) * 40 + ka]);
      acc[f] = __builtin_amdgcn_mfma_f32_16x16x32_bf16(a, b, acc[f], 0, 0, 0);
    }
    cur ^= 1;
  }
#pragma unroll
  for (int f = 0; f < 8; f++) {
#pragma unroll
    for (int r = 0; r < 4; r++) {
      int tl = w * 16 + ((lane >> 4) << 2) + r;
      int tok = mt * 64 + tl;
      float g = acc[f][r], u = acc[f + 8][r];
      float hval = (g / (1.f + __expf(-g))) * u;
      int h = ht * 128 + f * 16 + (lane & 15);
      hs[(size_t)(tok * NSH + s) * HSH + h] = f2bf(hval);
    }
  }
}

// ---------------- routed gate+up (+swiglu) ----------------
// grid (e=32, mt=32, ht=2), 256 thr. tile 64 x 256 (128 g | 128 u), K=1024.
__global__ __launch_bounds__(256) void k_routed_gu(const unsigned short* __restrict__ xb,
                                                   const float* __restrict__ Wg,
                                                   const float* __restrict__ Wu,
                                                   const int* __restrict__ cnt,
                                                   const int* __restrict__ ent,
                                                   const float* __restrict__ wgt,
                                                   unsigned short* __restrict__ hw) {
  int e = blockIdx.x, mt = blockIdx.y, ht = blockIdx.z;
  int ne = cnt[e * CNTS];
  if (mt * 64 >= ne) return;
  __shared__ unsigned short sA[2][64 * 40];
  __shared__ unsigned short sB[2][256 * 40];
  __shared__ int sTok[64];
  __shared__ float sW[64];
  int tid = threadIdx.x, lane = tid & 63, w = tid >> 6;
  if (tid < 64) {
    int pos = mt * 64 + tid;
    int p2 = min(pos, ne - 1);
    sTok[tid] = ent[e * N_TOK + p2];
    sW[tid] = (pos < ne) ? wgt[e * N_TOK + p2] : 0.f;
  }
  __syncthreads();

  int arow = tid >> 2, al4 = tid & 3;
  const unsigned short* aSrc = xb + (size_t)(sTok[arow] >> 2) * DDIM + al4 * 8;
  int br = tid >> 3, bl8 = tid & 7;
  const float* bSrc[8];
#pragma unroll
  for (int p = 0; p < 8; p++) {
    int h = ht * 128 + br + (p & 3) * 32;
    bSrc[p] = ((p >> 2) ? Wu : Wg) + (size_t)(e * HDIM + h) * DDIM + bl8 * 4;
  }

  us8 aReg = *reinterpret_cast<const us8*>(aSrc);
  float4 bReg[8];
#pragma unroll
  for (int p = 0; p < 8; p++) bReg[p] = *reinterpret_cast<const float4*>(bSrc[p]);

  f32x4 acc[16];
#pragma unroll
  for (int f = 0; f < 16; f++) acc[f] = {0.f, 0.f, 0.f, 0.f};

  int cur = 0;
  for (int step = 0; step < 32; ++step) {
    *reinterpret_cast<us8*>(&sA[cur][arow * 40 + al4 * 8]) = aReg;
#pragma unroll
    for (int p = 0; p < 8; p++) {
      int c = br + p * 32;
      *reinterpret_cast<us4*>(&sB[cur][c * 40 + bl8 * 4]) = cvt4(bReg[p]);
    }
    if (step < 31) {
      int k0 = (step + 1) * 32;
      aReg = *reinterpret_cast<const us8*>(aSrc + k0);
#pragma unroll
      for (int p = 0; p < 8; p++) bReg[p] = *reinterpret_cast<const float4*>(bSrc[p] + k0);
    }
    asm volatile("s_waitcnt lgkmcnt(0)" ::: "memory");
    __builtin_amdgcn_s_barrier();
    int ka = (lane >> 4) * 8;
    bf16x8 a = *reinterpret_cast<const bf16x8*>(&sA[cur][(w * 16 + (lane & 15)) * 40 + ka]);
#pragma unroll
    for (int f = 0; f < 16; f++) {
      bf16x8 b = *reinterpret_cast<const bf16x8*>(&sB[cur][(f * 16 + (lane & 15)) * 40 + ka]);
      acc[f] = __builtin_amdgcn_mfma_f32_16x16x32_bf16(a, b, acc[f], 0, 0, 0);
    }
    cur ^= 1;
  }
#pragma unroll
  for (int f = 0; f < 8; f++) {
#pragma unroll
    for (int r = 0; r < 4; r++) {
      int tl = w * 16 + ((lane >> 4) << 2) + r;
      int pos = mt * 64 + tl;
      if (pos < ne) {
        float g = acc[f][r], u = acc[f + 8][r];
        float hval = (g / (1.f + __expf(-g))) * u * sW[tl];
        int ts = sTok[tl];
        int h = ht * 128 + f * 16 + (lane & 15);
        hw[(size_t)ts * HDIM + h] = f2bf(hval);
      }
    }
  }
}

// ---------------- shared down-proj (bf16 partial per shared expert) ----------------
// grid (mt=32, dh=8, s=2), 256 thr. tile 64 x 128, K=1024.
__global__ __launch_bounds__(256) void k_shared_down(const unsigned short* __restrict__ hs,
                                                     const float* __restrict__ Sd,
                                                     unsigned short* __restrict__ Psh) {
  int mt = blockIdx.x, dh = blockIdx.y, s = blockIdx.z;
  __shared__ unsigned short sA[2][64 * 40];
  __shared__ unsigned short sB[2][128 * 40];
  int tid = threadIdx.x, lane = tid & 63, w = tid >> 6;

  int arow = tid >> 2, al4 = tid & 3;
  const unsigned short* aSrc = hs + (size_t)((mt * 64 + arow) * NSH + s) * HSH + al4 * 8;
  int br = tid >> 3, bl8 = tid & 7;
  const float* bSrc[4];
#pragma unroll
  for (int p = 0; p < 4; p++) {
    int d = dh * 128 + br + p * 32;
    bSrc[p] = Sd + (size_t)(s * DDIM + d) * HSH + bl8 * 4;
  }

  us8 aReg = *reinterpret_cast<const us8*>(aSrc);
  float4 bReg[4];
#pragma unroll
  for (int p = 0; p < 4; p++) bReg[p] = *reinterpret_cast<const float4*>(bSrc[p]);

  f32x4 acc[8];
#pragma unroll
  for (int f = 0; f < 8; f++) acc[f] = {0.f, 0.f, 0.f, 0.f};

  int cur = 0;
  for (int step = 0; step < 32; ++step) {
    *reinterpret_cast<us8*>(&sA[cur][arow * 40 + al4 * 8]) = aReg;
#pragma unroll
    for (int p = 0; p < 4; p++) {
      int c = br + p * 32;
      *reinterpret_cast<us4*>(&sB[cur][c * 40 + bl8 * 4]) = cvt4(bReg[p]);
    }
    if (step < 31) {
      int k0 = (step + 1) * 32;
      aReg = *reinterpret_cast<const us8*>(aSrc + k0);
#pragma unroll
      for (int p = 0; p < 4; p++) bReg[p] = *reinterpret_cast<const float4*>(bSrc[p] + k0);
    }
    asm volatile("s_waitcnt lgkmcnt(0)" ::: "memory");
    __builtin_amdgcn_s_barrier();
    int ka = (lane >> 4) * 8;
    bf16x8 a = *reinterpret_cast<const bf16x8*>(&sA[cur][(w * 16 + (lane & 15)) * 40 + ka]);
#pragma unroll
    for (int f = 0; f < 8; f++) {
      bf16x8 b = *reinterpret_cast<const bf16x8*>(&sB[cur][(f * 16 + (lane & 15)) * 40 + ka]);
      acc[f] = __builtin_amdgcn_mfma_f32_16x16x32_bf16(a, b, acc[f], 0, 0, 0);
    }
    cur ^= 1;
  }
#pragma unroll
  for (int f = 0; f < 8; f++) {
#pragma unroll
    for (int r = 0; r < 4; r++) {
      int tl = w * 16 + ((lane >> 4) << 2) + r;
      int tok = mt * 64 + tl;
      int d = dh * 128 + f * 16 + (lane & 15);
      Psh[(size_t)s * N_TOK * DDIM + (size_t)tok * DDIM + d] = f2bf(acc[f][r]);
    }
  }
}

// ---------------- routed down-proj (bf16 per-slot store) ----------------
// grid (e=32, mt=32, dh=8), 256 thr. tile 64 x 128, K=256.
__global__ __launch_bounds__(256) void k_routed_down(const unsigned short* __restrict__ hw,
                                                     const float* __restrict__ Wd,
                                                     const int* __restrict__ cnt,
                                                     const int* __restrict__ ent,
                                                     unsigned short* __restrict__ Pslot) {
  int e = blockIdx.x, mt = blockIdx.y, dh = blockIdx.z;
  int ne = cnt[e * CNTS];
  if (mt * 64 >= ne) return;
  __shared__ unsigned short sA[2][64 * 40];
  __shared__ unsigned short sB[2][128 * 40];
  __shared__ int sTok[64];
  int tid = threadIdx.x, lane = tid & 63, w = tid >> 6;
  if (tid < 64) {
    int pos = mt * 64 + tid;
    int p2 = min(pos, ne - 1);
    sTok[tid] = ent[e * N_TOK + p2];
  }
  __syncthreads();

  int arow = tid >> 2, al4 = tid & 3;
  const unsigned short* aSrc = hw + (size_t)sTok[arow] * HDIM + al4 * 8;
  int br = tid >> 3, bl8 = tid & 7;
  const float* bSrc[4];
#pragma unroll
  for (int p = 0; p < 4; p++) {
    int d = dh * 128 + br + p * 32;
    bSrc[p] = Wd + (size_t)(e * DDIM + d) * HDIM + bl8 * 4;
  }

  us8 aReg = *reinterpret_cast<const us8*>(aSrc);
  float4 bReg[4];
#pragma unroll
  for (int p = 0; p < 4; p++) bReg[p] = *reinterpret_cast<const float4*>(bSrc[p]);

  f32x4 acc[8];
#pragma unroll
  for (int f = 0; f < 8; f++) acc[f] = {0.f, 0.f, 0.f, 0.f};

  int cur = 0;
  for (int step = 0; step < 8; ++step) {
    *reinterpret_cast<us8*>(&sA[cur][arow * 40 + al4 * 8]) = aReg;
#pragma unroll
    for (int p = 0; p < 4; p++) {
      int c = br + p * 32;
      *reinterpret_cast<us4*>(&sB[cur][c * 40 + bl8 * 4]) = cvt4(bReg[p]);
    }
    if (step < 7) {
      int k0 = (step + 1) * 32;
      aReg = *reinterpret_cast<const us8*>(aSrc + k0);
#pragma unroll
      for (int p = 0; p < 4; p++) bReg[p] = *reinterpret_cast<const float4*>(bSrc[p] + k0);
    }
    asm volatile("s_waitcnt lgkmcnt(0)" ::: "memory");
    __builtin_amdgcn_s_barrier();
    int ka = (lane >> 4) * 8;
    bf16x8 a = *reinterpret_cast<const bf16x8*>(&sA[cur][(w * 16 + (lane & 15)) * 40 + ka]);
#pragma unroll
    for (int f = 0; f < 8; f++) {
      bf16x8 b = *reinterpret_cast<const bf16x8*>(&sB[cur][(f * 16 + (lane & 15)) * 40 + ka]);
      acc[f] = __builtin_amdgcn_mfma_f32_16x16x32_bf16(a, b, acc[f], 0, 0, 0);
    }
    cur ^= 1;
  }
#pragma unroll
  for (int f = 0; f < 8; f++) {
#pragma unroll
    for (int r = 0; r < 4; r++) {
      int tl = w * 16 + ((lane >> 4) << 2) + r;
      int pos = mt * 64 + tl;
      if (pos < ne) {
        int ts = sTok[tl];
        int d = dh * 128 + f * 16 + (lane & 15);
        Pslot[(size_t)ts * DDIM + d] = f2bf(acc[f][r]);
      }
    }
  }
}

// ---------------- final combine: out = Psh0 + Psh1 + sum_k Pslot[tok*4+k] ----------------
__global__ __launch_bounds__(256) void k_combine(const unsigned short* __restrict__ Pslot,
                                                 const unsigned short* __restrict__ Psh,
                                                 float* __restrict__ out) {
  int i = blockIdx.x * 256 + threadIdx.x;
  int base = i * 8;
  int tok = base >> 10, d = base & 1023;
  const us8 p0 = *reinterpret_cast<const us8*>(Pslot + ((size_t)tok * 4 + 0) * DDIM + d);
  const us8 p1 = *reinterpret_cast<const us8*>(Pslot + ((size_t)tok * 4 + 1) * DDIM + d);
  const us8 p2 = *reinterpret_cast<const us8*>(Pslot + ((size_t)tok * 4 + 2) * DDIM + d);
  const us8 p3 = *reinterpret_cast<const us8*>(Pslot + ((size_t)tok * 4 + 3) * DDIM + d);
  const us8 q0 = *reinterpret_cast<const us8*>(Psh + (size_t)base);
  const us8 q1 = *reinterpret_cast<const us8*>(Psh + (size_t)N_TOK * DDIM + base);
  float o[8];
#pragma unroll
  for (int j = 0; j < 8; j++)
    o[j] = bf2f(p0[j]) + bf2f(p1[j]) + bf2f(p2[j]) + bf2f(p3[j]) + bf2f(q0[j]) + bf2f(q1[j]);
  float4 v0 = {o[0], o[1], o[2], o[3]};
  float4 v1 = {o[4], o[5], o[6], o[7]};
  reinterpret_cast<float4*>(out + base)[0] = v0;
  reinterpret_cast<float4*>(out + base)[1] = v1;
}

extern "C" void kernel_launch(void* const* d_in, const int* in_sizes, int n_in,
                              void* d_out, int out_size, void* d_ws, size_t ws_size,
                              hipStream_t stream) {
  const float* x  = (const float*)d_in[0];
  const float* Wr = (const float*)d_in[1];
  const float* rb = (const float*)d_in[2];
  const float* Wg = (const float*)d_in[3];
  const float* Wu = (const float*)d_in[4];
  const float* Wd = (const float*)d_in[5];
  const float* Sg = (const float*)d_in[6];
  const float* Su = (const float*)d_in[7];
  const float* Sd = (const float*)d_in[8];
  float* out = (float*)d_out;
  char* w = (char*)d_ws;

  unsigned short* xb    = (unsigned short*)(w + (size_t)0);            // 4MB
  unsigned short* hw    = (unsigned short*)(w + ((size_t)4  << 20));   // 4MB
  unsigned short* hs    = (unsigned short*)(w + ((size_t)8  << 20));   // 8MB
  unsigned short* Pslot = (unsigned short*)(w + ((size_t)16 << 20));   // 16MB
  unsigned short* Psh   = (unsigned short*)(w + ((size_t)32 << 20));   // 8MB
  int*   cnt = (int*)(w + ((size_t)40 << 20));
  int*   ent = (int*)(w + ((size_t)40 << 20) + 8192);
  float* wgt = (float*)(w + ((size_t)40 << 20) + 8192 + (size_t)NEXP * N_TOK * 4);

  hipMemsetAsync(cnt, 0, NEXP * CNTS * sizeof(int), stream);

  {
    int n4 = N_TOK * DDIM / 4;
    k_cvt<<<(n4 + 255) / 256, 256, 0, stream>>>(x, xb, n4);
  }

  k_router2<<<N_TOK / 8, 256, 0, stream>>>(x, Wr, rb, cnt, ent, wgt);

  k_routed_gu<<<dim3(NEXP, 32, 2), 256, 0, stream>>>(xb, Wg, Wu, cnt, ent, wgt, hw);
  k_routed_down<<<dim3(NEXP, 32, 8), 256, 0, stream>>>(hw, Wd, cnt, ent, Pslot);

  k_shared_gu<<<dim3(32, 16), 256, 0, stream>>>(xb, Sg, Su, hs);
  k_shared_down<<<dim3(32, 8, 2), 256, 0, stream>>>(hs, Sd, Psh);

  k_combine<<<N_TOK * DDIM / (256 * 8), 256, 0, stream>>>(Pslot, Psh, out);
}